// Round 8
// baseline (1136.558 us; speedup 1.0000x reference)
//
#include <hip/hip_runtime.h>
#include <hip/hip_cooperative_groups.h>
#include <math.h>

namespace cg = cooperative_groups;

#define KT 512
#define VW 50257
#define DD 300
#define RR 75
#define DR 375
#define GAMMA 0.010187536f   // KT/VW — uniform gauge factor, cancels in row-normalize
#define SLOTS 8              // hierarchical atomic slots for row sums
#define CB 252               // cooperative blocks (252*200 >= VW), 1 block/CU
#define TC 200               // cols per thread (= cols per block; thread owns full rows)

typedef _Float16 half8 __attribute__((ext_vector_type(8)));
typedef float f32x4 __attribute__((ext_vector_type(4)));

__device__ __forceinline__ void load_lds16(const void* g, void* l) {
  __builtin_amdgcn_global_load_lds(
      (const __attribute__((address_space(1))) unsigned int*)g,
      (__attribute__((address_space(3))) unsigned int*)l, 16, 0, 0);
}

__device__ inline float block_reduce_sum(float val, float* sbuf) {
  int t = threadIdx.x;
  sbuf[t] = val;
  __syncthreads();
  for (int off = blockDim.x >> 1; off > 0; off >>= 1) {
    if (t < off) sbuf[t] += sbuf[t + off];
    __syncthreads();
  }
  float r = sbuf[0];
  __syncthreads();
  return r;
}

// DPP wave64 reduce-add: result lands in lane 63 (VALU pipe, no LDS traffic)
template <int CTRL>
__device__ __forceinline__ float dpp_add_step(float x) {
  int yi = __builtin_amdgcn_update_dpp(0, __float_as_int(x), CTRL, 0xf, 0xf, false);
  return x + __int_as_float(yi);
}
__device__ __forceinline__ float wave_reduce_add(float x) {
  x = dpp_add_step<0x111>(x);  // row_shr:1
  x = dpp_add_step<0x112>(x);  // row_shr:2
  x = dpp_add_step<0x114>(x);  // row_shr:4
  x = dpp_add_step<0x118>(x);  // row_shr:8
  x = dpp_add_step<0x142>(x);  // row_bcast:15
  x = dpp_add_step<0x143>(x);  // row_bcast:31
  return x;                    // lane 63 = full sum
}

// ---------- We [VW][300] f32 -> We2 [VW][640] fp16 = [hi(300)|pad|lo(300)|pad] ----------
__global__ void prep_We_split(const float* __restrict__ We, _Float16* __restrict__ We2) {
  int v = blockIdx.x, c = threadIdx.x;            // block 320 threads
  float x = (c < DD) ? We[(size_t)v * DD + c] : 0.f;
  _Float16 h = (_Float16)x;
  We2[(size_t)v * 640 + c] = h;
  We2[(size_t)v * 640 + 320 + c] = (_Float16)(x - (float)h);
}

// ---------- Bext_raw [375][300] f32 ----------
__global__ void prep_bext(const float* __restrict__ Wp, const float* __restrict__ MU,
                          float* __restrict__ Bext) {
  int id = blockIdx.x * blockDim.x + threadIdx.x;
  if (id >= DR * DD) return;
  int row = id / DD, d = id - row * DD;
  if (row < DD) {
    Bext[id] = Wp[row * DD + d];
  } else {
    int r = row - DD;
    float s = 0.f;
    for (int j = 0; j < DD; ++j) s += MU[j * RR + r] * Wp[j * DD + d];
    Bext[id] = s;
  }
}

// ---------- Bext2 [384][640] fp16 split (rows>=375 zero) ----------
__global__ void prep_bext_split(const float* __restrict__ BextR, _Float16* __restrict__ Bext2) {
  int r = blockIdx.x, c = threadIdx.x;            // 384 blocks x 320
  float x = (r < DR && c < DD) ? BextR[r * DD + c] : 0.f;
  _Float16 h = (_Float16)x;
  Bext2[(size_t)r * 640 + c] = h;
  Bext2[(size_t)r * 640 + 320 + c] = (_Float16)(x - (float)h);
}

// ---------- anchors -> Ahat2 [512][768] fp16 = [hi(384)|lo(384)], AA ----------
__global__ void prep_anchors(const float* __restrict__ anchors, const float* __restrict__ MU,
                             _Float16* __restrict__ Ahat2, float* __restrict__ AA) {
  __shared__ float a[DD];
  __shared__ float psh[RR];
  __shared__ float red[128];
  __shared__ float inv_sh;
  int k = blockIdx.x, t = threadIdx.x;
  float ss = 0.f;
  for (int d = t; d < DD; d += 128) {
    float x = anchors[k * DD + d];
    a[d] = x;
    ss += x * x;
  }
  ss = block_reduce_sum(ss, red);
  if (t == 0) inv_sh = 1.f / fmaxf(sqrtf(ss), 1e-12f);
  __syncthreads();
  float inv = inv_sh;
  float p2 = 0.f;
  if (t < RR) {
    float p = 0.f;
    for (int j = 0; j < DD; ++j) p += MU[j * RR + t] * a[j];
    p *= inv;
    psh[t] = p;
    p2 = p * p;
  }
  p2 = block_reduce_sum(p2, red);
  _Float16* row = Ahat2 + (size_t)k * 768;
  for (int d = t; d < 384; d += 128) {
    float val = (d < DD) ? a[d] * inv : ((d < DR) ? psh[d - DD] : 0.f);
    _Float16 h = (_Float16)val;
    row[d] = h;
    row[384 + d] = (_Float16)(val - (float)h);
  }
  if (t == 0) AA[k] = 1.f + p2;
}

// ---------- normalize What rows in place: f32 [VW][384] -> fp16 [VW][768], WW ----------
__global__ void prep_words(float* __restrict__ WhatR, float* __restrict__ WW) {
  __shared__ float red[128];
  __shared__ float inv_sh;
  int v = blockIdx.x, t = threadIdx.x;
  float* rowf = WhatR + (size_t)v * 384;
  float x0 = rowf[t];
  float x1 = rowf[t + 128];
  float x2 = (t + 256 < DR) ? rowf[t + 256] : 0.f;
  float ss = x0 * x0 + x1 * x1 + ((t < 44) ? x2 * x2 : 0.f);  // cols < 300
  ss = block_reduce_sum(ss, red);
  if (t == 0) inv_sh = 1.f / fmaxf(sqrtf(ss), 1e-12f);
  __syncthreads();
  float inv = inv_sh;
  x0 *= inv; x1 *= inv; x2 *= inv;
  float p2 = (t >= 44 && t + 256 < DR) ? x2 * x2 : 0.f;       // cols 300..374
  p2 = block_reduce_sum(p2, red);
  _Float16* rowh = (_Float16*)rowf;   // in-place: same 1536B footprint
  _Float16 h0 = (_Float16)x0;
  rowh[t] = h0; rowh[384 + t] = (_Float16)(x0 - (float)h0);
  _Float16 h1 = (_Float16)x1;
  rowh[128 + t] = h1; rowh[512 + t] = (_Float16)(x1 - (float)h1);
  float v2 = (t + 256 < DR) ? x2 : 0.f;
  _Float16 h2 = (_Float16)v2;
  rowh[256 + t] = h2; rowh[640 + t] = (_Float16)(v2 - (float)h2);
  if (t == 0) WW[v] = 1.f + p2;
}

// ---------- MFMA NT GEMM, split-fp16 3-term: A'=[hi|lo|hi], B'=[hi|hi|lo] ----------
// EPI==0: store C f32.  EPI==1: store E = min(exp((2C-AA-WW)/eps), 1)
template <int EPI>
__global__ __launch_bounds__(256) void gemm_mfma(
    const _Float16* __restrict__ Ag, int ldaE,
    const _Float16* __restrict__ Bg, int ldbE,
    float* __restrict__ C, long ldc,
    int M, int N, int KTOT, int SEGL, int mOnX,
    const float* __restrict__ AAv, const float* __restrict__ WWv,
    const float* __restrict__ log_eps_ptr) {
  __shared__ __align__(16) _Float16 As[128 * 64];
  __shared__ __align__(16) _Float16 Bs[128 * 64];
  int t = threadIdx.x, lane = t & 63, w = t >> 6;

  // XCD-chunked bijective swizzle (T1/m204): consecutive logical tiles -> same XCD
  int nwg = gridDim.x * gridDim.y;
  int orig = blockIdx.y * gridDim.x + blockIdx.x;
  int q = nwg >> 3, r8 = nwg & 7;
  int xcd = orig & 7, pos = orig >> 3;
  int wgid = (xcd < r8 ? xcd * (q + 1) : r8 * (q + 1) + (xcd - r8) * q) + pos;
  int bxi = wgid % gridDim.x;
  int byi = wgid / gridDim.x;

  int bm = (mOnX ? bxi : byi) * 128;
  int bn = (mOnX ? byi : bxi) * 128;
  int wm = w >> 1, wn = w & 1;
  f32x4 acc[4][4] = {};
  size_t ldaB = (size_t)ldaE * 2, ldbB = (size_t)ldbE * 2;
  int srow = lane >> 3, sg = lane & 7;
  int lr = lane & 15, kq = lane >> 4;

  for (int k0 = 0; k0 < KTOT; k0 += 64) {
    int ak = (k0 >= 2 * SEGL) ? k0 - 2 * SEGL : k0;
    int bk = (k0 >= SEGL) ? k0 - SEGL : k0;
    size_t akb = (size_t)ak * 2, bkb = (size_t)bk * 2;
#pragma unroll
    for (int qq = 0; qq < 4; ++qq) {
      int iid = w * 4 + qq;
      int r = iid * 8 + srow;
      int gs = sg ^ (r & 7);                 // pre-swizzled source granule
      int gmr = bm + r; if (gmr >= M) gmr = M - 1;
      load_lds16((const char*)Ag + (size_t)gmr * ldaB + akb + (gs << 4),
                 (char*)As + iid * 1024);
      int gnr = bn + r; if (gnr >= N) gnr = N - 1;
      load_lds16((const char*)Bg + (size_t)gnr * ldbB + bkb + (gs << 4),
                 (char*)Bs + iid * 1024);
    }
    __syncthreads();
#pragma unroll
    for (int ks = 0; ks < 2; ++ks) {
      half8 af[4], bf[4];
#pragma unroll
      for (int i = 0; i < 4; ++i) {
        int row = wm * 64 + i * 16 + lr;
        af[i] = *(const half8*)((const char*)As + row * 128 +
                                ((((ks << 2) + kq) ^ (row & 7)) << 4));
        int col = wn * 64 + i * 16 + lr;
        bf[i] = *(const half8*)((const char*)Bs + col * 128 +
                                ((((ks << 2) + kq) ^ (col & 7)) << 4));
      }
#pragma unroll
      for (int i = 0; i < 4; ++i)
#pragma unroll
        for (int j = 0; j < 4; ++j)
          acc[i][j] = __builtin_amdgcn_mfma_f32_16x16x32_f16(af[i], bf[j], acc[i][j], 0, 0, 0);
    }
    __syncthreads();
  }

  float s2e = 0.f;
  if (EPI == 1) {
    float le = log_eps_ptr[0];
    float eps = log1pf(__expf(le)) + 1e-4f;
    s2e = 1.4426950408889634f / eps;   // log2(e)/eps
  }
  int rq = lane >> 4;
#pragma unroll
  for (int i = 0; i < 4; ++i) {
#pragma unroll
    for (int j = 0; j < 4; ++j) {
#pragma unroll
      for (int r = 0; r < 4; ++r) {
        int gm = bm + wm * 64 + i * 16 + rq * 4 + r;
        int gn = bn + wn * 64 + j * 16 + lr;
        if (gm < M && gn < N) {
          float c = acc[i][j][r];
          if (EPI == 0) {
            C[(size_t)gm * ldc + gn] = c;
          } else {
            // E = exp(min(2C-AA-WW,0)/eps) = min(exp2((2C-AA-WW)*s2e), 1)
            float e = exp2f((2.f * c - AAv[gm] - WWv[gn]) * s2e);
            C[(size_t)gm * ldc + gn] = fminf(e, 1.0f);
          }
        }
      }
    }
  }
}

// ---------- Cooperative fused Sinkhorn: E register-resident across all 20 iterations ----
// 252 blocks x 512 threads, 1 block/CU, 2 waves/SIMD. Thread t = row t, owns
// tile[200] = E[t][200b .. 200b+200) — 200 VGPR, cap 256 at (512,2). Block owns all 512
// rows of its 200-col stripe -> colsum is block-local (DPP over 64-row waves + LDS
// combine across 8 waves). Rowsum is thread-local -> one slot-atomic per thread.
// One grid.sync per iteration.
__global__ __launch_bounds__(512, 2) void coop_sinkhorn(float* __restrict__ EB,
                                                        float* __restrict__ Sbuf) {
  cg::grid_group gg = cg::this_grid();
  __shared__ float colp[8][TC];
  __shared__ __align__(16) float v_sh[TC];
  int t = threadIdx.x;            // row index
  int w = t >> 6;                 // wave id (rows 64w..64w+63)
  int cbase = blockIdx.x * TC;
  float* base = EB + (size_t)t * VW + cbase;
  int slot = blockIdx.x & (SLOTS - 1);
  bool full = (cbase + TC <= VW);

  float tile[TC];
  if (full) {
#pragma unroll
    for (int j4 = 0; j4 < TC / 4; ++j4) {
      float4 x = *(const float4*)(base + j4 * 4);
      tile[j4 * 4 + 0] = x.x; tile[j4 * 4 + 1] = x.y;
      tile[j4 * 4 + 2] = x.z; tile[j4 * 4 + 3] = x.w;
    }
  } else {
#pragma unroll
    for (int j = 0; j < TC; ++j) tile[j] = (cbase + j < VW) ? base[j] : 0.f;
  }

  // initial row sums (v = 1) -> Sbuf[0]
  {
    float rs = 0.f;
#pragma unroll
    for (int j = 0; j < TC; ++j) rs += tile[j];
    unsafeAtomicAdd(&Sbuf[(size_t)slot * KT + t], rs);
    gg.sync();
  }

  for (int it = 1; it <= 20; ++it) {
    // u[t] = 1/rowsum_{it-1}
    const float* Sp = Sbuf + (size_t)(it - 1) * SLOTS * KT;
    float s = 0.f;
#pragma unroll
    for (int q = 0; q < SLOTS; ++q) s += Sp[q * KT + t];
    float u = 1.0f / fmaxf(s, 1e-35f);

    // colsum partials: per col j, DPP-reduce tile[j]*u over this wave's 64 rows
#pragma unroll
    for (int j = 0; j < TC; ++j) {
      float x = wave_reduce_add(tile[j] * u);
      if ((t & 63) == 63) colp[w][j] = x;
    }
    __syncthreads();
    if (t < TC) {
      float cs = 0.f;
#pragma unroll
      for (int q = 0; q < 8; ++q) cs += colp[q][t];
      v_sh[t] = GAMMA / fmaxf(cs, 1e-35f);
    }
    __syncthreads();

    // rowsum: sum_j tile[j] * v[j]  (v broadcast from LDS as float4)
    float rs = 0.f;
    const float4* vv4 = (const float4*)v_sh;
#pragma unroll
    for (int j4 = 0; j4 < TC / 4; ++j4) {
      float4 v4 = vv4[j4];
      rs = fmaf(tile[j4 * 4 + 0], v4.x, rs);
      rs = fmaf(tile[j4 * 4 + 1], v4.y, rs);
      rs = fmaf(tile[j4 * 4 + 2], v4.z, rs);
      rs = fmaf(tile[j4 * 4 + 3], v4.w, rs);
    }
    unsafeAtomicAdd(&Sbuf[(size_t)it * SLOTS * KT + slot * KT + t], rs);
    gg.sync();
  }

  // final: u' from Sbuf[20]; beta = tile * u' * v20 (v20 still in v_sh), in place
  {
    const float* Sp = Sbuf + (size_t)20 * SLOTS * KT;
    float s = 0.f;
#pragma unroll
    for (int q = 0; q < SLOTS; ++q) s += Sp[q * KT + t];
    float up = 1.0f / fmaxf(s, 1e-35f);
    if (full) {
#pragma unroll
      for (int j4 = 0; j4 < TC / 4; ++j4) {
        float4 o;
        o.x = tile[j4 * 4 + 0] * (up * v_sh[j4 * 4 + 0]);
        o.y = tile[j4 * 4 + 1] * (up * v_sh[j4 * 4 + 1]);
        o.z = tile[j4 * 4 + 2] * (up * v_sh[j4 * 4 + 2]);
        o.w = tile[j4 * 4 + 3] * (up * v_sh[j4 * 4 + 3]);
        *(float4*)(base + j4 * 4) = o;
      }
    } else {
#pragma unroll
      for (int j = 0; j < TC; ++j)
        if (cbase + j < VW) base[j] = tile[j] * (up * v_sh[j]);
    }
  }
}

extern "C" void kernel_launch(void* const* d_in, const int* in_sizes, int n_in,
                              void* d_out, int out_size, void* d_ws, size_t ws_size,
                              hipStream_t stream) {
  const float* We = (const float*)d_in[0];
  const float* An = (const float*)d_in[1];
  const float* MU = (const float*)d_in[2];
  const float* Wp = (const float*)d_in[3];
  const float* log_eps = (const float*)d_in[4];
  float* out = (float*)d_out;                    // holds E, then beta

  char* p = (char*)d_ws;
  auto take = [&](size_t b) { char* r = p; p += (b + 255) & ~(size_t)255; return r; };
  _Float16* We2   = (_Float16*)take((size_t)VW * 640 * 2);
  _Float16* Bext2 = (_Float16*)take((size_t)384 * 640 * 2);
  _Float16* Ahat2 = (_Float16*)take((size_t)KT * 768 * 2);
  float* WhatR    = (float*)take((size_t)VW * 384 * 4);  // aliased to What2 fp16 [VW][768]
  float* BextR    = (float*)take((size_t)DR * DD * 4);
  float* AA       = (float*)take(KT * 4);
  float* WW       = (float*)take((size_t)VW * 4);
  float* Sbuf     = (float*)take((size_t)21 * SLOTS * KT * 4);  // 21 stages x 8 slots x 512
  _Float16* What2 = (_Float16*)WhatR;

  // zero all stage accumulators once per launch (part of the captured graph)
  (void)hipMemsetAsync(Sbuf, 0, (size_t)21 * SLOTS * KT * 4, stream);

  prep_We_split<<<VW, 320, 0, stream>>>(We, We2);
  prep_bext<<<(DR * DD + 255) / 256, 256, 0, stream>>>(Wp, MU, BextR);
  prep_bext_split<<<384, 320, 0, stream>>>(BextR, Bext2);
  prep_anchors<<<KT, 128, 0, stream>>>(An, MU, Ahat2, AA);

  // What_raw[v][0..383] = We' @ Bext'^T   (M=VW, N=384, K'=960, SEG=320)
  gemm_mfma<0><<<dim3(3, 393), 256, 0, stream>>>(
      We2, 640, Bext2, 640, WhatR, 384, VW, 384, 960, 320, 0,
      nullptr, nullptr, nullptr);

  prep_words<<<VW, 128, 0, stream>>>(WhatR, WW);

  // E = exp(min(2*Ahat@What^T - AA - WW,0)/eps)   (M=KT, N=VW, K'=1152, SEG=384)
  gemm_mfma<1><<<dim3(4, 393), 256, 0, stream>>>(
      Ahat2, 768, What2, 768, out, VW, KT, VW, 1152, 384, 1,
      AA, WW, log_eps);

  // Entire Sinkhorn + beta write in one cooperative kernel (E in registers)
  void* kargs[] = {(void*)&out, (void*)&Sbuf};
  (void)hipLaunchCooperativeKernel((void*)coop_sinkhorn, dim3(CB), dim3(512),
                                   kargs, 0, stream);
}

// Round 9
// 862.329 us; speedup vs baseline: 1.3180x; 1.3180x over previous
//
#include <hip/hip_runtime.h>
#include <math.h>

#define KT 512
#define VW 50257
#define DD 300
#define RR 75
#define DR 375
#define GAMMA 0.010187536f   // KT/VW — uniform gauge factor, cancels in row-normalize
#define NB 786               // ceil(VW/64) sweep stripes
#define SLOTS 8              // hierarchical atomic slots for row sums

typedef _Float16 half8 __attribute__((ext_vector_type(8)));
typedef float f32x4 __attribute__((ext_vector_type(4)));
// 4-byte-aligned float4 view: E rows are only 4B aligned (VW odd). Compiler emits
// dwordx4 when legal for the target, else splits into dwords — correct either way.
typedef float f4a __attribute__((ext_vector_type(4), aligned(4)));

__device__ __forceinline__ void load_lds16(const void* g, void* l) {
  __builtin_amdgcn_global_load_lds(
      (const __attribute__((address_space(1))) unsigned int*)g,
      (__attribute__((address_space(3))) unsigned int*)l, 16, 0, 0);
}

__device__ inline float block_reduce_sum(float val, float* sbuf) {
  int t = threadIdx.x;
  sbuf[t] = val;
  __syncthreads();
  for (int off = blockDim.x >> 1; off > 0; off >>= 1) {
    if (t < off) sbuf[t] += sbuf[t + off];
    __syncthreads();
  }
  float r = sbuf[0];
  __syncthreads();
  return r;
}

// DPP add step: lane i += lane (i-N) within its 16-lane DPP row; OOB lanes add 0
template <int CTRL>
__device__ __forceinline__ float dpp_add_step(float x) {
  int yi = __builtin_amdgcn_update_dpp(0, __float_as_int(x), CTRL, 0xf, 0xf, false);
  return x + __int_as_float(yi);
}
// 16-lane inclusive reduce: lane 15 (mod 16) holds the 16-lane sum
__device__ __forceinline__ float row16_reduce_add(float x) {
  x = dpp_add_step<0x111>(x);  // row_shr:1
  x = dpp_add_step<0x112>(x);  // row_shr:2
  x = dpp_add_step<0x114>(x);  // row_shr:4
  x = dpp_add_step<0x118>(x);  // row_shr:8
  return x;
}

// ---------- We [VW][300] f32 -> We2 [VW][640] fp16 = [hi(300)|pad|lo(300)|pad] ----------
__global__ void prep_We_split(const float* __restrict__ We, _Float16* __restrict__ We2) {
  int v = blockIdx.x, c = threadIdx.x;            // block 320 threads
  float x = (c < DD) ? We[(size_t)v * DD + c] : 0.f;
  _Float16 h = (_Float16)x;
  We2[(size_t)v * 640 + c] = h;
  We2[(size_t)v * 640 + 320 + c] = (_Float16)(x - (float)h);
}

// ---------- Bext_raw [375][300] f32 ----------
__global__ void prep_bext(const float* __restrict__ Wp, const float* __restrict__ MU,
                          float* __restrict__ Bext) {
  int id = blockIdx.x * blockDim.x + threadIdx.x;
  if (id >= DR * DD) return;
  int row = id / DD, d = id - row * DD;
  if (row < DD) {
    Bext[id] = Wp[row * DD + d];
  } else {
    int r = row - DD;
    float s = 0.f;
    for (int j = 0; j < DD; ++j) s += MU[j * RR + r] * Wp[j * DD + d];
    Bext[id] = s;
  }
}

// ---------- Bext2 [384][640] fp16 split (rows>=375 zero) ----------
__global__ void prep_bext_split(const float* __restrict__ BextR, _Float16* __restrict__ Bext2) {
  int r = blockIdx.x, c = threadIdx.x;            // 384 blocks x 320
  float x = (r < DR && c < DD) ? BextR[r * DD + c] : 0.f;
  _Float16 h = (_Float16)x;
  Bext2[(size_t)r * 640 + c] = h;
  Bext2[(size_t)r * 640 + 320 + c] = (_Float16)(x - (float)h);
}

// ---------- anchors -> Ahat2 [512][768] fp16 = [hi(384)|lo(384)], AA ----------
__global__ void prep_anchors(const float* __restrict__ anchors, const float* __restrict__ MU,
                             _Float16* __restrict__ Ahat2, float* __restrict__ AA) {
  __shared__ float a[DD];
  __shared__ float psh[RR];
  __shared__ float red[128];
  __shared__ float inv_sh;
  int k = blockIdx.x, t = threadIdx.x;
  float ss = 0.f;
  for (int d = t; d < DD; d += 128) {
    float x = anchors[k * DD + d];
    a[d] = x;
    ss += x * x;
  }
  ss = block_reduce_sum(ss, red);
  if (t == 0) inv_sh = 1.f / fmaxf(sqrtf(ss), 1e-12f);
  __syncthreads();
  float inv = inv_sh;
  float p2 = 0.f;
  if (t < RR) {
    float p = 0.f;
    for (int j = 0; j < DD; ++j) p += MU[j * RR + t] * a[j];
    p *= inv;
    psh[t] = p;
    p2 = p * p;
  }
  p2 = block_reduce_sum(p2, red);
  _Float16* row = Ahat2 + (size_t)k * 768;
  for (int d = t; d < 384; d += 128) {
    float val = (d < DD) ? a[d] * inv : ((d < DR) ? psh[d - DD] : 0.f);
    _Float16 h = (_Float16)val;
    row[d] = h;
    row[384 + d] = (_Float16)(val - (float)h);
  }
  if (t == 0) AA[k] = 1.f + p2;
}

// ---------- normalize What rows in place: f32 [VW][384] -> fp16 [VW][768], WW ----------
__global__ void prep_words(float* __restrict__ WhatR, float* __restrict__ WW) {
  __shared__ float red[128];
  __shared__ float inv_sh;
  int v = blockIdx.x, t = threadIdx.x;
  float* rowf = WhatR + (size_t)v * 384;
  float x0 = rowf[t];
  float x1 = rowf[t + 128];
  float x2 = (t + 256 < DR) ? rowf[t + 256] : 0.f;
  float ss = x0 * x0 + x1 * x1 + ((t < 44) ? x2 * x2 : 0.f);  // cols < 300
  ss = block_reduce_sum(ss, red);
  if (t == 0) inv_sh = 1.f / fmaxf(sqrtf(ss), 1e-12f);
  __syncthreads();
  float inv = inv_sh;
  x0 *= inv; x1 *= inv; x2 *= inv;
  float p2 = (t >= 44 && t + 256 < DR) ? x2 * x2 : 0.f;       // cols 300..374
  p2 = block_reduce_sum(p2, red);
  _Float16* rowh = (_Float16*)rowf;   // in-place: same 1536B footprint
  _Float16 h0 = (_Float16)x0;
  rowh[t] = h0; rowh[384 + t] = (_Float16)(x0 - (float)h0);
  _Float16 h1 = (_Float16)x1;
  rowh[128 + t] = h1; rowh[512 + t] = (_Float16)(x1 - (float)h1);
  float v2 = (t + 256 < DR) ? x2 : 0.f;
  _Float16 h2 = (_Float16)v2;
  rowh[256 + t] = h2; rowh[640 + t] = (_Float16)(v2 - (float)h2);
  if (t == 0) WW[v] = 1.f + p2;
}

// ---------- MFMA NT GEMM, split-fp16 3-term, 2-phase double-buffered staging ----------
// EPI==0: store C f32.  EPI==1: store E = min(exp((2C-AA-WW)/eps), 1)
template <int EPI>
__global__ __launch_bounds__(256) void gemm_mfma(
    const _Float16* __restrict__ Ag, int ldaE,
    const _Float16* __restrict__ Bg, int ldbE,
    float* __restrict__ C, long ldc,
    int M, int N, int KTOT, int SEGL, int mOnX,
    const float* __restrict__ AAv, const float* __restrict__ WWv,
    const float* __restrict__ log_eps_ptr) {
  __shared__ __align__(16) _Float16 As[2 * 128 * 64];
  __shared__ __align__(16) _Float16 Bs[2 * 128 * 64];
  int t = threadIdx.x, lane = t & 63, w = t >> 6;

  // XCD-chunked bijective swizzle (T1/m204)
  int nwg = gridDim.x * gridDim.y;
  int orig = blockIdx.y * gridDim.x + blockIdx.x;
  int q = nwg >> 3, r8 = nwg & 7;
  int xcd = orig & 7, pos = orig >> 3;
  int wgid = (xcd < r8 ? xcd * (q + 1) : r8 * (q + 1) + (xcd - r8) * q) + pos;
  int bxi = wgid % gridDim.x;
  int byi = wgid / gridDim.x;

  int bm = (mOnX ? bxi : byi) * 128;
  int bn = (mOnX ? byi : bxi) * 128;
  int wm = w >> 1, wn = w & 1;
  f32x4 acc[4][4] = {};
  size_t ldaB = (size_t)ldaE * 2, ldbB = (size_t)ldbE * 2;
  int srow = lane >> 3, sg = lane & 7;
  int lr = lane & 15, kq = lane >> 4;
  int NT = KTOT >> 6;

  auto stage = [&](int buf, int kt) {
    int k0 = kt << 6;
    int ak = (k0 >= 2 * SEGL) ? k0 - 2 * SEGL : k0;
    int bk = (k0 >= SEGL) ? k0 - SEGL : k0;
    size_t akb = (size_t)ak * 2, bkb = (size_t)bk * 2;
#pragma unroll
    for (int qq = 0; qq < 4; ++qq) {
      int iid = w * 4 + qq;
      int r = iid * 8 + srow;
      int gs = sg ^ (r & 7);                 // pre-swizzled source granule
      int gmr = bm + r; if (gmr >= M) gmr = M - 1;
      load_lds16((const char*)Ag + (size_t)gmr * ldaB + akb + (gs << 4),
                 (char*)As + buf * 16384 + iid * 1024);
      int gnr = bn + r; if (gnr >= N) gnr = N - 1;
      load_lds16((const char*)Bg + (size_t)gnr * ldbB + bkb + (gs << 4),
                 (char*)Bs + buf * 16384 + iid * 1024);
    }
  };

  stage(0, 0);
  __syncthreads();                 // drain prologue loads
  int cur = 0;
  for (int kt = 0; kt < NT; ++kt) {
    if (kt + 1 < NT) stage(cur ^ 1, kt + 1);   // issue next tile early
    const char* Ab = (const char*)As + cur * 16384;
    const char* Bb = (const char*)Bs + cur * 16384;
#pragma unroll
    for (int ks = 0; ks < 2; ++ks) {
      half8 af[4], bf[4];
#pragma unroll
      for (int i = 0; i < 4; ++i) {
        int row = wm * 64 + i * 16 + lr;
        af[i] = *(const half8*)(Ab + row * 128 +
                                ((((ks << 2) + kq) ^ (row & 7)) << 4));
        int col = wn * 64 + i * 16 + lr;
        bf[i] = *(const half8*)(Bb + col * 128 +
                                ((((ks << 2) + kq) ^ (col & 7)) << 4));
      }
#pragma unroll
      for (int i = 0; i < 4; ++i)
#pragma unroll
        for (int j = 0; j < 4; ++j)
          acc[i][j] = __builtin_amdgcn_mfma_f32_16x16x32_f16(af[i], bf[j], acc[i][j], 0, 0, 0);
    }
    __syncthreads();               // drains next-tile loads; guards buffer reuse
    cur ^= 1;
  }

  float s2e = 0.f;
  if (EPI == 1) {
    float le = log_eps_ptr[0];
    float eps = log1pf(__expf(le)) + 1e-4f;
    s2e = 1.4426950408889634f / eps;   // log2(e)/eps
  }
  int rq = lane >> 4;
#pragma unroll
  for (int i = 0; i < 4; ++i) {
#pragma unroll
    for (int j = 0; j < 4; ++j) {
#pragma unroll
      for (int r = 0; r < 4; ++r) {
        int gm = bm + wm * 64 + i * 16 + rq * 4 + r;
        int gn = bn + wn * 64 + j * 16 + lr;
        if (gm < M && gn < N) {
          float c = acc[i][j][r];
          if (EPI == 0) {
            C[(size_t)gm * ldc + gn] = c;
          } else {
            float e = exp2f((2.f * c - AAv[gm] - WWv[gn]) * s2e);
            C[(size_t)gm * ldc + gn] = fminf(e, 1.0f);
          }
        }
      }
    }
  }
}

// ---------- Fused Sinkhorn sweep (float4): one kernel = [v_j = γ/(Eᵀu_j); rowsums E·v_j] ----
// Block b: cols [64b, 64b+64), all 512 rows. Thread t: c4=t&15 (col quad), rg=t>>4.
// tl[16] = float4 of cols [4c4,4c4+4) at rows rg+32j. Wave instr = 1KB contiguous.
// Rowsum partial: dot(tl,v) -> 16-lane DPP reduce (lane c4==15). Colsum via LDS combine.
template <int FIRST>
__global__ __launch_bounds__(512) void sweep(const float* __restrict__ E,
                                             const float* __restrict__ Sprev,
                                             float* __restrict__ Scur,
                                             float* __restrict__ vout) {
  __shared__ float u_sh[KT];
  __shared__ __align__(16) float colp[32][64];
  __shared__ __align__(16) float v_sh[64];
  __shared__ float rowacc[KT];
  int t = threadIdx.x;
  int c4 = t & 15, rg = t >> 4;
  int c0 = blockIdx.x * 64;
  int colb = c0 + c4 * 4;
  bool full = (c0 + 64 <= VW);

  float4 tl[16];
  const float* bp = E + (size_t)rg * VW + colb;
  if (full) {
#pragma unroll
    for (int j = 0; j < 16; ++j) {
      f4a x = *(const f4a*)bp;
      tl[j] = make_float4(x.x, x.y, x.z, x.w);
      bp += (size_t)32 * VW;
    }
  } else {
#pragma unroll
    for (int j = 0; j < 16; ++j) {
      float4 x;
      x.x = (colb + 0 < VW) ? bp[0] : 0.f;
      x.y = (colb + 1 < VW) ? bp[1] : 0.f;
      x.z = (colb + 2 < VW) ? bp[2] : 0.f;
      x.w = (colb + 3 < VW) ? bp[3] : 0.f;
      tl[j] = x;
      bp += (size_t)32 * VW;
    }
  }

  float4 vq;
  if (FIRST) {
    vq = make_float4(1.f, 1.f, 1.f, 1.f);
  } else {
    float s = 0.f;
#pragma unroll
    for (int q = 0; q < SLOTS; ++q) s += Sprev[q * KT + t];
    u_sh[t] = 1.0f / fmaxf(s, 1e-35f);
    __syncthreads();
    // colsum partials over this thread's 16 rows
    float4 cs = make_float4(0.f, 0.f, 0.f, 0.f);
#pragma unroll
    for (int j = 0; j < 16; ++j) {
      float u = u_sh[rg + 32 * j];
      cs.x = fmaf(tl[j].x, u, cs.x);
      cs.y = fmaf(tl[j].y, u, cs.y);
      cs.z = fmaf(tl[j].z, u, cs.z);
      cs.w = fmaf(tl[j].w, u, cs.w);
    }
    *(float4*)&colp[rg][c4 * 4] = cs;
    __syncthreads();
    if (t < 64) {
      float s2 = 0.f;
#pragma unroll
      for (int q = 0; q < 32; ++q) s2 += colp[q][t];
      float vv = (c0 + t < VW) ? GAMMA / fmaxf(s2, 1e-35f) : 0.f;
      v_sh[t] = vv;
      if (c0 + t < VW) vout[c0 + t] = vv;
    }
    __syncthreads();
    vq = *(const float4*)&v_sh[c4 * 4];
  }

  // rowsum partials: per j, dot then 16-lane DPP reduce (lane c4==15 holds sum)
#pragma unroll
  for (int j = 0; j < 16; ++j) {
    float x = fmaf(tl[j].x, vq.x, fmaf(tl[j].y, vq.y,
              fmaf(tl[j].z, vq.z, tl[j].w * vq.w)));
    x = row16_reduce_add(x);
    if (c4 == 15) rowacc[rg + 32 * j] = x;
  }
  __syncthreads();
  unsafeAtomicAdd(&Scur[(size_t)(blockIdx.x & (SLOTS - 1)) * KT + t], rowacc[t]);
}

// ---------- beta = E * u'[k] * vv[v] in place (u' combined from final S slots) ----------
__global__ __launch_bounds__(256) void write_beta(float* __restrict__ out,
                                                  const float* __restrict__ Sfin,
                                                  const float* __restrict__ vv) {
  __shared__ float uk_sh;
  int k = blockIdx.y;
  int t = threadIdx.x;
  if (t == 0) {
    float s = 0.f;
#pragma unroll
    for (int q = 0; q < SLOTS; ++q) s += Sfin[q * KT + k];
    uk_sh = 1.0f / fmaxf(s, 1e-35f);
  }
  __syncthreads();
  float uk = uk_sh;
  int v4 = (blockIdx.x * 256 + t) * 4;
  if (v4 + 4 <= VW) {
    size_t id = (size_t)k * VW + v4;
    f4a e = *(const f4a*)(out + id);
    float4 w = *(const float4*)(vv + v4);
    f4a o;
    o.x = e.x * (uk * w.x); o.y = e.y * (uk * w.y);
    o.z = e.z * (uk * w.z); o.w = e.w * (uk * w.w);
    *(f4a*)(out + id) = o;
  } else {
#pragma unroll
    for (int j = 0; j < 4; ++j) {
      if (v4 + j < VW) {
        size_t id = (size_t)k * VW + v4 + j;
        out[id] = out[id] * (uk * vv[v4 + j]);
      }
    }
  }
}

extern "C" void kernel_launch(void* const* d_in, const int* in_sizes, int n_in,
                              void* d_out, int out_size, void* d_ws, size_t ws_size,
                              hipStream_t stream) {
  const float* We = (const float*)d_in[0];
  const float* An = (const float*)d_in[1];
  const float* MU = (const float*)d_in[2];
  const float* Wp = (const float*)d_in[3];
  const float* log_eps = (const float*)d_in[4];
  float* out = (float*)d_out;                    // holds E, then beta

  char* p = (char*)d_ws;
  auto take = [&](size_t b) { char* r = p; p += (b + 255) & ~(size_t)255; return r; };
  _Float16* We2   = (_Float16*)take((size_t)VW * 640 * 2);
  _Float16* Bext2 = (_Float16*)take((size_t)384 * 640 * 2);
  _Float16* Ahat2 = (_Float16*)take((size_t)KT * 768 * 2);
  float* WhatR    = (float*)take((size_t)VW * 384 * 4);  // aliased to What2 fp16 [VW][768]
  float* BextR    = (float*)take((size_t)DR * DD * 4);
  float* AA       = (float*)take(KT * 4);
  float* WW       = (float*)take((size_t)VW * 4);
  float* Sbuf     = (float*)take((size_t)21 * SLOTS * KT * 4);  // 21 stages x 8 slots x 512
  float* VVb      = (float*)take((size_t)VW * 4);
  _Float16* What2 = (_Float16*)WhatR;

  (void)hipMemsetAsync(Sbuf, 0, (size_t)21 * SLOTS * KT * 4, stream);

  prep_We_split<<<VW, 320, 0, stream>>>(We, We2);
  prep_bext<<<(DR * DD + 255) / 256, 256, 0, stream>>>(Wp, MU, BextR);
  prep_bext_split<<<384, 320, 0, stream>>>(BextR, Bext2);
  prep_anchors<<<KT, 128, 0, stream>>>(An, MU, Ahat2, AA);

  // What_raw[v][0..383] = We' @ Bext'^T   (M=VW, N=384, K'=960, SEG=320)
  gemm_mfma<0><<<dim3(3, 393), 256, 0, stream>>>(
      We2, 640, Bext2, 640, WhatR, 384, VW, 384, 960, 320, 0,
      nullptr, nullptr, nullptr);

  prep_words<<<VW, 128, 0, stream>>>(WhatR, WW);

  // E = exp(min(2*Ahat@What^T - AA - WW,0)/eps)   (M=KT, N=VW, K'=1152, SEG=384)
  gemm_mfma<1><<<dim3(4, 393), 256, 0, stream>>>(
      Ahat2, 768, What2, 768, out, VW, KT, VW, 1152, 384, 1,
      AA, WW, log_eps);

  // Sinkhorn: sweep 0 = initial row sums (v=1); sweeps 1..20 = [v_j; rowsums -> u_{j+1}]
  sweep<1><<<NB, 512, 0, stream>>>(out, nullptr, Sbuf, nullptr);
  for (int s = 1; s <= 20; ++s) {
    sweep<0><<<NB, 512, 0, stream>>>(out, Sbuf + (size_t)(s - 1) * SLOTS * KT,
                                     Sbuf + (size_t)s * SLOTS * KT, VVb);
  }

  // beta = E * u' * v20  (u' = 1/S_20 combined in-kernel)
  dim3 g3((VW + 1023) / 1024, KT);
  write_beta<<<g3, 256, 0, stream>>>(out, Sbuf + (size_t)20 * SLOTS * KT, VVb);
}

// Round 10
// 854.359 us; speedup vs baseline: 1.3303x; 1.0093x over previous
//
#include <hip/hip_runtime.h>
#include <math.h>

#define KT 512
#define VW 50257
#define DD 300
#define RR 75
#define DR 375
#define GAMMA 0.010187536f   // KT/VW — uniform gauge factor, cancels in row-normalize
#define NBS 393              // ceil(VW/128) sweep stripes
#define SLOTS 8              // hierarchical atomic slots for row sums

typedef _Float16 half8 __attribute__((ext_vector_type(8)));
typedef float f32x4 __attribute__((ext_vector_type(4)));
// 4-byte-aligned float4 view: E rows are only 4B aligned (VW odd).
typedef float f4a __attribute__((ext_vector_type(4), aligned(4)));

__device__ __forceinline__ void load_lds16(const void* g, void* l) {
  __builtin_amdgcn_global_load_lds(
      (const __attribute__((address_space(1))) unsigned int*)g,
      (__attribute__((address_space(3))) unsigned int*)l, 16, 0, 0);
}

__device__ inline float block_reduce_sum(float val, float* sbuf) {
  int t = threadIdx.x;
  sbuf[t] = val;
  __syncthreads();
  for (int off = blockDim.x >> 1; off > 0; off >>= 1) {
    if (t < off) sbuf[t] += sbuf[t + off];
    __syncthreads();
  }
  float r = sbuf[0];
  __syncthreads();
  return r;
}

// DPP add step: zero-fill OOB (old=0), so shr-steps build prefix sums
template <int CTRL>
__device__ __forceinline__ float dpp_add_step(float x) {
  int yi = __builtin_amdgcn_update_dpp(0, __float_as_int(x), CTRL, 0xf, 0xf, false);
  return x + __int_as_float(yi);
}
// 16-lane reduce: lane 15 (mod 16) holds its 16-lane group sum
__device__ __forceinline__ float row16_reduce_add(float x) {
  x = dpp_add_step<0x111>(x);  // row_shr:1
  x = dpp_add_step<0x112>(x);  // row_shr:2
  x = dpp_add_step<0x114>(x);  // row_shr:4
  x = dpp_add_step<0x118>(x);  // row_shr:8
  return x;
}
// 32-lane reduce: lanes 31 and 63 hold their 32-lane group sums
__device__ __forceinline__ float row32_reduce_add(float x) {
  x = row16_reduce_add(x);
  x = dpp_add_step<0x142>(x);  // row_bcast:15 — lane31 += lane15, lane63 += lane47
  return x;
}

// ---------- We [VW][300] f32 -> We2 [VW][640] fp16 = [hi(300)|pad|lo(300)|pad] ----------
__global__ void prep_We_split(const float* __restrict__ We, _Float16* __restrict__ We2) {
  int v = blockIdx.x, c = threadIdx.x;            // block 320 threads
  float x = (c < DD) ? We[(size_t)v * DD + c] : 0.f;
  _Float16 h = (_Float16)x;
  We2[(size_t)v * 640 + c] = h;
  We2[(size_t)v * 640 + 320 + c] = (_Float16)(x - (float)h);
}

// ---------- Bext_raw [375][300] f32 ----------
__global__ void prep_bext(const float* __restrict__ Wp, const float* __restrict__ MU,
                          float* __restrict__ Bext) {
  int id = blockIdx.x * blockDim.x + threadIdx.x;
  if (id >= DR * DD) return;
  int row = id / DD, d = id - row * DD;
  if (row < DD) {
    Bext[id] = Wp[row * DD + d];
  } else {
    int r = row - DD;
    float s = 0.f;
    for (int j = 0; j < DD; ++j) s += MU[j * RR + r] * Wp[j * DD + d];
    Bext[id] = s;
  }
}

// ---------- Bext2 [384][640] fp16 split (rows>=375 zero) ----------
__global__ void prep_bext_split(const float* __restrict__ BextR, _Float16* __restrict__ Bext2) {
  int r = blockIdx.x, c = threadIdx.x;            // 384 blocks x 320
  float x = (r < DR && c < DD) ? BextR[r * DD + c] : 0.f;
  _Float16 h = (_Float16)x;
  Bext2[(size_t)r * 640 + c] = h;
  Bext2[(size_t)r * 640 + 320 + c] = (_Float16)(x - (float)h);
}

// ---------- anchors -> Ahat2 [512][768] fp16 = [hi(384)|lo(384)], AA ----------
__global__ void prep_anchors(const float* __restrict__ anchors, const float* __restrict__ MU,
                             _Float16* __restrict__ Ahat2, float* __restrict__ AA) {
  __shared__ float a[DD];
  __shared__ float psh[RR];
  __shared__ float red[128];
  __shared__ float inv_sh;
  int k = blockIdx.x, t = threadIdx.x;
  float ss = 0.f;
  for (int d = t; d < DD; d += 128) {
    float x = anchors[k * DD + d];
    a[d] = x;
    ss += x * x;
  }
  ss = block_reduce_sum(ss, red);
  if (t == 0) inv_sh = 1.f / fmaxf(sqrtf(ss), 1e-12f);
  __syncthreads();
  float inv = inv_sh;
  float p2 = 0.f;
  if (t < RR) {
    float p = 0.f;
    for (int j = 0; j < DD; ++j) p += MU[j * RR + t] * a[j];
    p *= inv;
    psh[t] = p;
    p2 = p * p;
  }
  p2 = block_reduce_sum(p2, red);
  _Float16* row = Ahat2 + (size_t)k * 768;
  for (int d = t; d < 384; d += 128) {
    float val = (d < DD) ? a[d] * inv : ((d < DR) ? psh[d - DD] : 0.f);
    _Float16 h = (_Float16)val;
    row[d] = h;
    row[384 + d] = (_Float16)(val - (float)h);
  }
  if (t == 0) AA[k] = 1.f + p2;
}

// ---------- normalize What rows in place: f32 [VW][384] -> fp16 [VW][768], WW ----------
__global__ void prep_words(float* __restrict__ WhatR, float* __restrict__ WW) {
  __shared__ float red[128];
  __shared__ float inv_sh;
  int v = blockIdx.x, t = threadIdx.x;
  float* rowf = WhatR + (size_t)v * 384;
  float x0 = rowf[t];
  float x1 = rowf[t + 128];
  float x2 = (t + 256 < DR) ? rowf[t + 256] : 0.f;
  float ss = x0 * x0 + x1 * x1 + ((t < 44) ? x2 * x2 : 0.f);  // cols < 300
  ss = block_reduce_sum(ss, red);
  if (t == 0) inv_sh = 1.f / fmaxf(sqrtf(ss), 1e-12f);
  __syncthreads();
  float inv = inv_sh;
  x0 *= inv; x1 *= inv; x2 *= inv;
  float p2 = (t >= 44 && t + 256 < DR) ? x2 * x2 : 0.f;       // cols 300..374
  p2 = block_reduce_sum(p2, red);
  _Float16* rowh = (_Float16*)rowf;   // in-place: same 1536B footprint
  _Float16 h0 = (_Float16)x0;
  rowh[t] = h0; rowh[384 + t] = (_Float16)(x0 - (float)h0);
  _Float16 h1 = (_Float16)x1;
  rowh[128 + t] = h1; rowh[512 + t] = (_Float16)(x1 - (float)h1);
  float v2 = (t + 256 < DR) ? x2 : 0.f;
  _Float16 h2 = (_Float16)v2;
  rowh[256 + t] = h2; rowh[640 + t] = (_Float16)(v2 - (float)h2);
  if (t == 0) WW[v] = 1.f + p2;
}

// ---------- MFMA NT GEMM, split-fp16 3-term: A'=[hi|lo|hi], B'=[hi|hi|lo] ----------
// EPI==0: store C f32.  EPI==1: store E = min(exp((2C-AA-WW)/eps), 1) AND
//         accumulate per-row partial sums of E into Sb0 (fused Sinkhorn sweep 0).
template <int EPI>
__global__ __launch_bounds__(256) void gemm_mfma(
    const _Float16* __restrict__ Ag, int ldaE,
    const _Float16* __restrict__ Bg, int ldbE,
    float* __restrict__ C, long ldc,
    int M, int N, int KTOT, int SEGL, int mOnX,
    const float* __restrict__ AAv, const float* __restrict__ WWv,
    const float* __restrict__ log_eps_ptr, float* __restrict__ Sb0) {
  __shared__ __align__(16) _Float16 As[128 * 64];
  __shared__ __align__(16) _Float16 Bs[128 * 64];
  __shared__ float epart[128][2];
  int t = threadIdx.x, lane = t & 63, w = t >> 6;

  // XCD-chunked bijective swizzle (T1/m204)
  int nwg = gridDim.x * gridDim.y;
  int orig = blockIdx.y * gridDim.x + blockIdx.x;
  int q = nwg >> 3, r8 = nwg & 7;
  int xcd = orig & 7, pos = orig >> 3;
  int wgid = (xcd < r8 ? xcd * (q + 1) : r8 * (q + 1) + (xcd - r8) * q) + pos;
  int bxi = wgid % gridDim.x;
  int byi = wgid / gridDim.x;

  int bm = (mOnX ? bxi : byi) * 128;
  int bn = (mOnX ? byi : bxi) * 128;
  int wm = w >> 1, wn = w & 1;
  f32x4 acc[4][4] = {};
  size_t ldaB = (size_t)ldaE * 2, ldbB = (size_t)ldbE * 2;
  int srow = lane >> 3, sg = lane & 7;
  int lr = lane & 15, kq = lane >> 4;

  for (int k0 = 0; k0 < KTOT; k0 += 64) {
    int ak = (k0 >= 2 * SEGL) ? k0 - 2 * SEGL : k0;
    int bk = (k0 >= SEGL) ? k0 - SEGL : k0;
    size_t akb = (size_t)ak * 2, bkb = (size_t)bk * 2;
#pragma unroll
    for (int qq = 0; qq < 4; ++qq) {
      int iid = w * 4 + qq;
      int r = iid * 8 + srow;
      int gs = sg ^ (r & 7);                 // pre-swizzled source granule
      int gmr = bm + r; if (gmr >= M) gmr = M - 1;
      load_lds16((const char*)Ag + (size_t)gmr * ldaB + akb + (gs << 4),
                 (char*)As + iid * 1024);
      int gnr = bn + r; if (gnr >= N) gnr = N - 1;
      load_lds16((const char*)Bg + (size_t)gnr * ldbB + bkb + (gs << 4),
                 (char*)Bs + iid * 1024);
    }
    __syncthreads();
#pragma unroll
    for (int ks = 0; ks < 2; ++ks) {
      half8 af[4], bf[4];
#pragma unroll
      for (int i = 0; i < 4; ++i) {
        int row = wm * 64 + i * 16 + lr;
        af[i] = *(const half8*)((const char*)As + row * 128 +
                                ((((ks << 2) + kq) ^ (row & 7)) << 4));
        int col = wn * 64 + i * 16 + lr;
        bf[i] = *(const half8*)((const char*)Bs + col * 128 +
                                ((((ks << 2) + kq) ^ (col & 7)) << 4));
      }
#pragma unroll
      for (int i = 0; i < 4; ++i)
#pragma unroll
        for (int j = 0; j < 4; ++j)
          acc[i][j] = __builtin_amdgcn_mfma_f32_16x16x32_f16(af[i], bf[j], acc[i][j], 0, 0, 0);
    }
    __syncthreads();
  }

  float s2e = 0.f;
  if (EPI == 1) {
    float le = log_eps_ptr[0];
    float eps = log1pf(__expf(le)) + 1e-4f;
    s2e = 1.4426950408889634f / eps;   // log2(e)/eps
  }
  int rq = lane >> 4;
#pragma unroll
  for (int i = 0; i < 4; ++i) {
#pragma unroll
    for (int r = 0; r < 4; ++r) {
      int gm = bm + wm * 64 + i * 16 + rq * 4 + r;
      float se = 0.f;
#pragma unroll
      for (int j = 0; j < 4; ++j) {
        int gn = bn + wn * 64 + j * 16 + lr;
        float c = acc[i][j][r];
        if (EPI == 0) {
          if (gm < M && gn < N) C[(size_t)gm * ldc + gn] = c;
        } else {
          float e = exp2f((2.f * c - AAv[gm < M ? gm : 0] -
                           WWv[gn < N ? gn : 0]) * s2e);
          e = fminf(e, 1.0f);
          if (gn >= N) e = 0.f;               // OOB cols contribute 0 to rowsum
          if (gm < M && gn < N) C[(size_t)gm * ldc + gn] = e;
          se += e;
        }
      }
      if (EPI == 1) {
        se = row16_reduce_add(se);            // sum over lr (16 lanes = 64 cols w/ j)
        if (lr == 15) epart[wm * 64 + i * 16 + rq * 4 + r][wn] = se;
      }
    }
  }
  if (EPI == 1) {
    __syncthreads();
    if (t < 128) {
      int slot = wgid & (SLOTS - 1);
      unsafeAtomicAdd(&Sb0[(size_t)slot * KT + bm + t], epart[t][0] + epart[t][1]);
    }
  }
}

// ---------- Fused Sinkhorn sweep (128-col stripes, 1024 threads) ----------
// Block b: cols [128b, 128b+128), all 512 rows. Thread t: c4=t&31 (col quad),
// rg=t>>5 (row group 0..31). tl[16] = float4 of rows rg+32j. 512B/row-visit.
// v = γ/colsum block-local; rowsum via 32-lane DPP reduce -> slot atomics.
__global__ __launch_bounds__(1024) void sweep(const float* __restrict__ E,
                                              const float* __restrict__ Sprev,
                                              float* __restrict__ Scur,
                                              float* __restrict__ vout) {
  __shared__ float u_sh[KT];
  __shared__ __align__(16) float colp[32][128];
  __shared__ __align__(16) float v_sh[128];
  __shared__ float rowacc[KT];
  int t = threadIdx.x;
  int c4 = t & 31, rg = t >> 5;
  int c0 = blockIdx.x * 128;
  int colb = c0 + c4 * 4;
  bool full = (c0 + 128 <= VW);

  if (t < KT) {
    float s = 0.f;
#pragma unroll
    for (int q = 0; q < SLOTS; ++q) s += Sprev[q * KT + t];
    u_sh[t] = 1.0f / fmaxf(s, 1e-35f);
  }

  float4 tl[16];
  const float* bp = E + (size_t)rg * VW + colb;
  if (full) {
#pragma unroll
    for (int j = 0; j < 16; ++j) {
      f4a x = *(const f4a*)bp;
      tl[j] = make_float4(x.x, x.y, x.z, x.w);
      bp += (size_t)32 * VW;
    }
  } else {
#pragma unroll
    for (int j = 0; j < 16; ++j) {
      float4 x;
      x.x = (colb + 0 < VW) ? bp[0] : 0.f;
      x.y = (colb + 1 < VW) ? bp[1] : 0.f;
      x.z = (colb + 2 < VW) ? bp[2] : 0.f;
      x.w = (colb + 3 < VW) ? bp[3] : 0.f;
      tl[j] = x;
      bp += (size_t)32 * VW;
    }
  }
  __syncthreads();   // u_sh ready

  // colsum partials over this thread's 16 rows
  float4 cs = make_float4(0.f, 0.f, 0.f, 0.f);
#pragma unroll
  for (int j = 0; j < 16; ++j) {
    float u = u_sh[rg + 32 * j];
    cs.x = fmaf(tl[j].x, u, cs.x);
    cs.y = fmaf(tl[j].y, u, cs.y);
    cs.z = fmaf(tl[j].z, u, cs.z);
    cs.w = fmaf(tl[j].w, u, cs.w);
  }
  *(float4*)&colp[rg][c4 * 4] = cs;
  __syncthreads();
  if (t < 128) {
    float s2 = 0.f;
#pragma unroll
    for (int q = 0; q < 32; ++q) s2 += colp[q][t];
    float vv = (c0 + t < VW) ? GAMMA / fmaxf(s2, 1e-35f) : 0.f;
    v_sh[t] = vv;
    if (c0 + t < VW) vout[c0 + t] = vv;
  }
  __syncthreads();
  float4 vq = *(const float4*)&v_sh[c4 * 4];

  // rowsum partials: per j, dot then 32-lane DPP reduce (lanes t&31==31 hold sums)
#pragma unroll
  for (int j = 0; j < 16; ++j) {
    float x = fmaf(tl[j].x, vq.x, fmaf(tl[j].y, vq.y,
              fmaf(tl[j].z, vq.z, tl[j].w * vq.w)));
    x = row32_reduce_add(x);
    if ((t & 31) == 31) rowacc[rg + 32 * j] = x;
  }
  __syncthreads();
  if (t < KT)
    unsafeAtomicAdd(&Scur[(size_t)(blockIdx.x & (SLOTS - 1)) * KT + t], rowacc[t]);
}

// ---------- beta = E * u'[k] * vv[v] in place (u' combined from final S slots) ----------
__global__ __launch_bounds__(256) void write_beta(float* __restrict__ out,
                                                  const float* __restrict__ Sfin,
                                                  const float* __restrict__ vv) {
  __shared__ float uk_sh;
  int k = blockIdx.y;
  int t = threadIdx.x;
  if (t == 0) {
    float s = 0.f;
#pragma unroll
    for (int q = 0; q < SLOTS; ++q) s += Sfin[q * KT + k];
    uk_sh = 1.0f / fmaxf(s, 1e-35f);
  }
  __syncthreads();
  float uk = uk_sh;
  int v4 = (blockIdx.x * 256 + t) * 4;
  if (v4 + 4 <= VW) {
    size_t id = (size_t)k * VW + v4;
    f4a e = *(const f4a*)(out + id);
    float4 w = *(const float4*)(vv + v4);
    f4a o;
    o.x = e.x * (uk * w.x); o.y = e.y * (uk * w.y);
    o.z = e.z * (uk * w.z); o.w = e.w * (uk * w.w);
    *(f4a*)(out + id) = o;
  } else {
#pragma unroll
    for (int j = 0; j < 4; ++j) {
      if (v4 + j < VW) {
        size_t id = (size_t)k * VW + v4 + j;
        out[id] = out[id] * (uk * vv[v4 + j]);
      }
    }
  }
}

extern "C" void kernel_launch(void* const* d_in, const int* in_sizes, int n_in,
                              void* d_out, int out_size, void* d_ws, size_t ws_size,
                              hipStream_t stream) {
  const float* We = (const float*)d_in[0];
  const float* An = (const float*)d_in[1];
  const float* MU = (const float*)d_in[2];
  const float* Wp = (const float*)d_in[3];
  const float* log_eps = (const float*)d_in[4];
  float* out = (float*)d_out;                    // holds E, then beta

  char* p = (char*)d_ws;
  auto take = [&](size_t b) { char* r = p; p += (b + 255) & ~(size_t)255; return r; };
  _Float16* We2   = (_Float16*)take((size_t)VW * 640 * 2);
  _Float16* Bext2 = (_Float16*)take((size_t)384 * 640 * 2);
  _Float16* Ahat2 = (_Float16*)take((size_t)KT * 768 * 2);
  float* WhatR    = (float*)take((size_t)VW * 384 * 4);  // aliased to What2 fp16 [VW][768]
  float* BextR    = (float*)take((size_t)DR * DD * 4);
  float* AA       = (float*)take(KT * 4);
  float* WW       = (float*)take((size_t)VW * 4);
  float* Sbuf     = (float*)take((size_t)21 * SLOTS * KT * 4);  // 21 stages x 8 slots x 512
  float* VVb      = (float*)take((size_t)VW * 4);
  _Float16* What2 = (_Float16*)WhatR;

  (void)hipMemsetAsync(Sbuf, 0, (size_t)21 * SLOTS * KT * 4, stream);

  prep_We_split<<<VW, 320, 0, stream>>>(We, We2);
  prep_bext<<<(DR * DD + 255) / 256, 256, 0, stream>>>(Wp, MU, BextR);
  prep_bext_split<<<384, 320, 0, stream>>>(BextR, Bext2);
  prep_anchors<<<KT, 128, 0, stream>>>(An, MU, Ahat2, AA);

  // What_raw[v][0..383] = We' @ Bext'^T   (M=VW, N=384, K'=960, SEG=320)
  gemm_mfma<0><<<dim3(3, 393), 256, 0, stream>>>(
      We2, 640, Bext2, 640, WhatR, 384, VW, 384, 960, 320, 0,
      nullptr, nullptr, nullptr, nullptr);

  prep_words<<<VW, 128, 0, stream>>>(WhatR, WW);

  // E = exp(min(2*Ahat@What^T - AA - WW,0)/eps); fused initial rowsums -> Sbuf[0]
  gemm_mfma<1><<<dim3(4, 393), 256, 0, stream>>>(
      Ahat2, 768, What2, 768, out, VW, KT, VW, 1152, 384, 1,
      AA, WW, log_eps, Sbuf);

  // Sinkhorn sweeps 1..20: [u_j = 1/S_{j-1}; v_j = γ/(Eᵀu_j); S_j = rowsums(E·v_j)]
  for (int s = 1; s <= 20; ++s) {
    sweep<<<NBS, 1024, 0, stream>>>(out, Sbuf + (size_t)(s - 1) * SLOTS * KT,
                                    Sbuf + (size_t)s * SLOTS * KT, VVb);
  }

  // beta = E * u' * v20  (u' = 1/S_20 combined in-kernel)
  dim3 g3((VW + 1023) / 1024, KT);
  write_beta<<<g3, 256, 0, stream>>>(out, Sbuf + (size_t)20 * SLOTS * KT, VVb);
}